// Round 2
// baseline (1423.197 us; speedup 1.0000x reference)
//
#include <hip/hip_runtime.h>

// SimpleLSTM persistent kernel: 256 WGs (one per batch element), 512 threads each.
// W_hh held on-CU as f16: k[0,192) in VGPRs (192 regs/thread), k[192,256) in LDS
// (XOR-swizzled 16B slots). MACs via v_dot2_f32_f16, f32 accumulation.

typedef _Float16 h16;
typedef _Float16 h2_t __attribute__((ext_vector_type(2)));
typedef _Float16 h8_t __attribute__((ext_vector_type(8)));

#if defined(__has_builtin)
#  if __has_builtin(__builtin_amdgcn_fdot2)
#    define FDOT2(a, b, c) __builtin_amdgcn_fdot2((a), (b), (c), false)
#  endif
#endif
#ifndef FDOT2
__device__ __forceinline__ float fdot2_sw(h2_t a, h2_t b, float c) {
  return c + (float)a.x * (float)b.x + (float)a.y * (float)b.y;
}
#  define FDOT2(a, b, c) fdot2_sw((a), (b), (c))
#endif

__device__ __forceinline__ float fast_sigmoid(float x) {
  // 1/(1+2^(-x*log2e)); saturates gracefully (rcp(inf)=0)
  return __builtin_amdgcn_rcpf(1.0f + __builtin_amdgcn_exp2f(-1.44269504f * x));
}
__device__ __forceinline__ float fast_tanh(float x) {
  // 1 - 2/(2^(2x*log2e)+1)
  return 1.0f - 2.0f * __builtin_amdgcn_rcpf(1.0f + __builtin_amdgcn_exp2f(2.88539008f * x));
}

union V8 { h8_t v; h2_t p[4]; };

#define NSTEPS 512
#define KRREG  192          // k-range in VGPRs per gate-row
#define RC     (KRREG / 8)  // 24 register chunks of 8
// LDS part: k in [192,256): 8 chunks of 8 halfs per row, 64-half (128 B) row slot

__global__ __launch_bounds__(512, 2) void lstm_persist(
    const float* __restrict__ X, const float* __restrict__ W_ih,
    const float* __restrict__ W_hh, const float* __restrict__ b_ih,
    const float* __restrict__ b_hh, const float* __restrict__ W_dense,
    const float* __restrict__ b_dense, float* __restrict__ out) {
  __shared__ alignas(16) h16 wlds[1024 * 64];  // 128 KiB swizzled W_hh tail
  __shared__ alignas(16) h16 hbuf[256];        // h_t as f16
  __shared__ float fo_lds[512];                // f gates [0,256), o gates [256,512)
  __shared__ float red[4][3];                  // dense-head wave partials

  const int t = threadIdx.x;   // 0..511; owns gate rows t and t+512
  const int b = blockIdx.x;    // batch element

  // ---------------- init: pack weights ----------------
  h2_t wreg[2][KRREG / 2];  // 192 VGPRs of f16 pairs
#pragma unroll
  for (int row = 0; row < 2; ++row) {
    const float* wr = W_hh + (size_t)(t + row * 512) * 256;
#pragma unroll
    for (int kk = 0; kk < RC; ++kk) {
      float4 a = ((const float4*)wr)[kk * 2];
      float4 c4 = ((const float4*)wr)[kk * 2 + 1];
      h2_t w0; w0.x = (h16)a.x;  w0.y = (h16)a.y;
      h2_t w1; w1.x = (h16)a.z;  w1.y = (h16)a.w;
      h2_t w2; w2.x = (h16)c4.x; w2.y = (h16)c4.y;
      h2_t w3; w3.x = (h16)c4.z; w3.y = (h16)c4.w;
      wreg[row][kk * 4 + 0] = w0;
      wreg[row][kk * 4 + 1] = w1;
      wreg[row][kk * 4 + 2] = w2;
      wreg[row][kk * 4 + 3] = w3;
    }
  }
  // LDS tail of W_hh, XOR-swizzled so phase-A ds_read_b128 is conflict-free
#pragma unroll
  for (int row = 0; row < 2; ++row) {
    const int r = t + row * 512;
    const float* wr = W_hh + (size_t)r * 256 + KRREG;
#pragma unroll
    for (int c = 0; c < 8; ++c) {
      float4 a = ((const float4*)wr)[c * 2];
      float4 d = ((const float4*)wr)[c * 2 + 1];
      h8_t w8;
      w8[0] = (h16)a.x; w8[1] = (h16)a.y; w8[2] = (h16)a.z; w8[3] = (h16)a.w;
      w8[4] = (h16)d.x; w8[5] = (h16)d.y; w8[6] = (h16)d.z; w8[7] = (h16)d.w;
      const int slot = c ^ (r & 7);
      *(h8_t*)(&wlds[r * 64 + slot * 8]) = w8;
    }
  }
  // W_ih rows as f16 pairs (F=10 -> 5 pairs per row)
  h2_t wih[2][5];
#pragma unroll
  for (int row = 0; row < 2; ++row) {
    const float* wr = W_ih + (size_t)(t + row * 512) * 10;
#pragma unroll
    for (int p = 0; p < 5; ++p) {
      h2_t w; w.x = (h16)wr[2 * p]; w.y = (h16)wr[2 * p + 1];
      wih[row][p] = w;
    }
  }
  const float bias0 = b_ih[t] + b_hh[t];
  const float bias1 = b_ih[t + 512] + b_hh[t + 512];
  float wd0 = 0.f, wd1 = 0.f, wd2 = 0.f, bd = 0.f, c_state = 0.f;
  if (t < 256) {
    wd0 = W_dense[t];            // W_dense[0][t]
    wd1 = W_dense[256 + t];      // W_dense[1][t]
    wd2 = W_dense[512 + t];      // W_dense[2][t]
    hbuf[t] = (h16)0.f;          // h0 = 0
  }
  if (t < 3) bd = b_dense[t];

  const float* Xb = X + (size_t)b * (NSTEPS * 10);
  float* outb = out + (size_t)b * (NSTEPS * 3);
  const int base0 = t * 64;
  const int base1 = (t + 512) * 64;
  const int sw = t & 7;

  __syncthreads();

  // ---------------- time loop ----------------
  for (int step = 0; step < NSTEPS; ++step) {
    // Phase A: gates for rows t (acc0) and t+512 (acc1); split accumulators to
    // relax the fdot2 dependency chain.
    float acc0[2]; acc0[0] = bias0; acc0[1] = 0.f;
    float acc1[2]; acc1[0] = bias1; acc1[1] = 0.f;

    {  // input projection, x_t is wave-uniform (L1/sL1 resident)
      const float* xp = Xb + step * 10;
#pragma unroll
      for (int p = 0; p < 5; ++p) {
        h2_t xh; xh.x = (h16)xp[2 * p]; xh.y = (h16)xp[2 * p + 1];
        acc0[0] = FDOT2(xh, wih[0][p], acc0[0]);
        acc1[0] = FDOT2(xh, wih[1][p], acc1[0]);
      }
    }
    // register-resident k in [0,192)
#pragma unroll
    for (int kk = 0; kk < RC; ++kk) {
      V8 u; u.v = *(const h8_t*)(&hbuf[kk * 8]);
      const int pa = kk & 1;
#pragma unroll
      for (int p = 0; p < 4; ++p) {
        acc0[pa] = FDOT2(u.p[p], wreg[0][kk * 4 + p], acc0[pa]);
        acc1[pa] = FDOT2(u.p[p], wreg[1][kk * 4 + p], acc1[pa]);
      }
    }
    // LDS-resident k in [192,256)
#pragma unroll
    for (int c = 0; c < 8; ++c) {
      V8 u; u.v = *(const h8_t*)(&hbuf[(RC + c) * 8]);
      const int slot = (c ^ sw) * 8;
      V8 w0; w0.v = *(const h8_t*)(&wlds[base0 + slot]);
      V8 w1; w1.v = *(const h8_t*)(&wlds[base1 + slot]);
      const int pa = c & 1;
#pragma unroll
      for (int p = 0; p < 4; ++p) {
        acc0[pa] = FDOT2(u.p[p], w0.p[p], acc0[pa]);
        acc1[pa] = FDOT2(u.p[p], w1.p[p], acc1[pa]);
      }
    }
    const float g0 = acc0[0] + acc0[1];
    const float g1 = acc1[0] + acc1[1];

    // Phase B: threads >=256 publish f,o; threads <256 own (i,g) locally.
    if (t >= 256) {
      fo_lds[t - 256] = g0;  // f_{t-256}
      fo_lds[t] = g1;        // o_{t-256} at [256 + j]
    }
    __syncthreads();  // [1] fo visible; all hbuf reads of this step complete
    if (t < 256) {
      const float ig = fast_sigmoid(g0);
      const float gg = fast_tanh(g1);
      const float fg = fast_sigmoid(fo_lds[t]);
      const float og = fast_sigmoid(fo_lds[256 + t]);
      c_state = fg * c_state + ig * gg;
      const float h = og * fast_tanh(c_state);
      hbuf[t] = (h16)h;  // safe: all readers passed barrier [1]
      // dense head: 3 dot products over the 256 hidden units
      float p0 = h * wd0, p1 = h * wd1, p2 = h * wd2;
#pragma unroll
      for (int m = 32; m > 0; m >>= 1) {
        p0 += __shfl_xor(p0, m);
        p1 += __shfl_xor(p1, m);
        p2 += __shfl_xor(p2, m);
      }
      if ((t & 63) == 0) {
        red[t >> 6][0] = p0; red[t >> 6][1] = p1; red[t >> 6][2] = p2;
      }
    }
    __syncthreads();  // [2] h_{t+1} + head partials visible
    if (t < 3) {
      outb[step * 3 + t] = red[0][t] + red[1][t] + red[2][t] + red[3][t] + bd;
    }
  }
}

extern "C" void kernel_launch(void* const* d_in, const int* in_sizes, int n_in,
                              void* d_out, int out_size, void* d_ws, size_t ws_size,
                              hipStream_t stream) {
  const float* X       = (const float*)d_in[0];
  const float* W_ih    = (const float*)d_in[1];
  const float* W_hh    = (const float*)d_in[2];
  const float* b_ih    = (const float*)d_in[3];
  const float* b_hh    = (const float*)d_in[4];
  const float* W_dense = (const float*)d_in[5];
  const float* b_dense = (const float*)d_in[6];
  lstm_persist<<<dim3(256), dim3(512), 0, stream>>>(
      X, W_ih, W_hh, b_ih, b_hh, W_dense, b_dense, (float*)d_out);
}